// Round 7
// baseline (194.450 us; speedup 1.0000x reference)
//
#include <hip/hip_runtime.h>
#include <hip/hip_bf16.h>

// Round 7: identical to round 6 (container unresponsive; no signal).

typedef __attribute__((ext_vector_type(4))) float floatx4;
typedef __attribute__((ext_vector_type(8))) short short8;
typedef __attribute__((ext_vector_type(8))) unsigned short ushortx8;

#define K1 2048
#define N1 1024

__device__ __forceinline__ unsigned short f2bf(float f) {
  __hip_bfloat16 h = __float2bfloat16(f);
  return __builtin_bit_cast(unsigned short, h);
}

__device__ __forceinline__ void gload_lds16(const void* g, void* l) {
  __builtin_amdgcn_global_load_lds(
      (__attribute__((address_space(1))) void*)const_cast<void*>(g),
      (__attribute__((address_space(3))) void*)l, 16, 0, 0);
}

__global__ void cvt_bf16_kernel(const float* __restrict__ src,
                                unsigned short* __restrict__ dst, int n4) {
  int i = blockIdx.x * blockDim.x + threadIdx.x;
  if (i >= n4) return;
  float4 f = reinterpret_cast<const float4*>(src)[i];
  ushort4 o;
  o.x = f2bf(f.x); o.y = f2bf(f.y); o.z = f2bf(f.z); o.w = f2bf(f.w);
  reinterpret_cast<ushort4*>(dst)[i] = o;
}

// Gather + fp32->bf16: xb[row][k] = bf16(tok[idxs[row]][k]). One block per row.
__global__ __launch_bounds__(256) void gather_cvt_kernel(
    const int* __restrict__ idxs, const float* __restrict__ tok,
    unsigned short* __restrict__ xb) {
  const int row = blockIdx.x;
  const float* src = tok + (size_t)idxs[row] * K1;
  unsigned short* dst = xb + (size_t)row * K1;
  const int o = threadIdx.x * 8;
  const float4 f0 = *reinterpret_cast<const float4*>(src + o);
  const float4 f1 = *reinterpret_cast<const float4*>(src + o + 4);
  ushortx8 u;
  u[0] = f2bf(f0.x); u[1] = f2bf(f0.y); u[2] = f2bf(f0.z); u[3] = f2bf(f0.w);
  u[4] = f2bf(f1.x); u[5] = f2bf(f1.y); u[6] = f2bf(f1.z); u[7] = f2bf(f1.w);
  *reinterpret_cast<ushortx8*>(dst + o) = u;
}

// 256x256-tile GEMM, BK=64, 8 waves (2Mx4N), 4-phase interleaved K-loop with
// counted vmcnt (T3+T4), setprio around MFMA clusters (T5), st-swizzled LDS
// (T2, via pre-swizzled global source per rule #21), XCD-swizzled grid (T1).
template <int KDIM, int EPI>
__global__ __launch_bounds__(512, 2) void gemm256_kernel(
    const unsigned short* __restrict__ A, const unsigned short* __restrict__ Bw,
    const float* __restrict__ bias, void* __restrict__ outp) {
  __shared__ unsigned short Asub[2][16384];
  __shared__ unsigned short Bsub[2][16384];
  const int t = threadIdx.x;
  const int p = blockIdx.x;
  const int bid = (p & 7) * 32 + (p >> 3);  // XCD x owns contiguous bm range
  const int bm = bid >> 2, bn = bid & 3;
  const int brow0 = bm * 256, bcol0 = bn * 256;
  const int lane = t & 63, w = t >> 6;
  const int wm = w >> 2, wn = w & 3;  // per-wave C: 128x64
  const int fr = lane & 15, kg2 = lane >> 4;

  // staging source: row r = (t>>3)+64q, global chunk cg = (t&7) ^ (r&7)
  const int srow = t >> 3;
  const int cg = (t & 7) ^ (srow & 7);
  const unsigned short* aq[4];
  const unsigned short* bq[4];
#pragma unroll
  for (int q = 0; q < 4; ++q) {
    aq[q] = A + (size_t)(brow0 + srow + 64 * q) * KDIM + cg * 8;
    bq[q] = Bw + (size_t)(bcol0 + srow + 64 * q) * KDIM + cg * 8;
  }
  const int t8 = t * 8;  // linear LDS dest (shorts)

  // fragment read bases (shorts): row r at r*64; chunk c stored at slot c^(r&7)
  const int arow_sh = (wm * 128 + fr) * 64;
  const int brow_sh = (wn * 64 + fr) * 64;

  floatx4 acc[8][4] = {};
  constexpr int NT = KDIM / 64;

// issue one A+B chunk pair (literal P keeps aq/bq indexing static, rule #20)
#define ISSUE_PAIR(d, k0, P)                                   \
  do {                                                         \
    gload_lds16(aq[P] + (k0), &Asub[d][t8 + (P)*4096]);        \
    gload_lds16(bq[P] + (k0), &Bsub[d][t8 + (P)*4096]);        \
  } while (0)

// one phase: optional B-frag reload, 4 A-frags, 16 MFMA, pacing barrier.
// KS, I0, LOADB are literals -> all acc/array indexing static (rule #20).
#define MFMA_PHASE(cur, KS, I0, LOADB)                                        \
  do {                                                                        \
    const int sl = (((KS)*4 + kg2) ^ (fr & 7)) * 8;                           \
    short8 af0, af1, af2, af3;                                                \
    if (LOADB) {                                                              \
      bf[0] = *(const short8*)&Bsub[cur][brow_sh + 0 * 1024 + sl];            \
      bf[1] = *(const short8*)&Bsub[cur][brow_sh + 1 * 1024 + sl];            \
      bf[2] = *(const short8*)&Bsub[cur][brow_sh + 2 * 1024 + sl];            \
      bf[3] = *(const short8*)&Bsub[cur][brow_sh + 3 * 1024 + sl];            \
    }                                                                         \
    af0 = *(const short8*)&Asub[cur][arow_sh + ((I0) + 0) * 1024 + sl];       \
    af1 = *(const short8*)&Asub[cur][arow_sh + ((I0) + 1) * 1024 + sl];       \
    af2 = *(const short8*)&Asub[cur][arow_sh + ((I0) + 2) * 1024 + sl];       \
    af3 = *(const short8*)&Asub[cur][arow_sh + ((I0) + 3) * 1024 + sl];       \
    asm volatile("s_waitcnt lgkmcnt(0)" ::: "memory");                        \
    __builtin_amdgcn_sched_barrier(0);                                        \
    __builtin_amdgcn_s_setprio(1);                                            \
    _Pragma("unroll") for (int j = 0; j < 4; ++j) {                           \
      acc[(I0) + 0][j] = __builtin_amdgcn_mfma_f32_16x16x32_bf16(af0, bf[j], acc[(I0) + 0][j], 0, 0, 0); \
      acc[(I0) + 1][j] = __builtin_amdgcn_mfma_f32_16x16x32_bf16(af1, bf[j], acc[(I0) + 1][j], 0, 0, 0); \
      acc[(I0) + 2][j] = __builtin_amdgcn_mfma_f32_16x16x32_bf16(af2, bf[j], acc[(I0) + 2][j], 0, 0, 0); \
      acc[(I0) + 3][j] = __builtin_amdgcn_mfma_f32_16x16x32_bf16(af3, bf[j], acc[(I0) + 3][j], 0, 0, 0); \
    }                                                                         \
    __builtin_amdgcn_s_setprio(0);                                            \
    __builtin_amdgcn_sched_barrier(0);                                        \
    asm volatile("s_barrier" ::: "memory");                                   \
  } while (0)

  // prologue: stage tile 0 (8 loads)
  ISSUE_PAIR(0, 0, 0);
  ISSUE_PAIR(0, 0, 1);
  ISSUE_PAIR(0, 0, 2);
  ISSUE_PAIR(0, 0, 3);

#pragma unroll 1
  for (int tt = 0; tt < NT; ++tt) {
    const int cur = tt & 1;
    const int nbuf = cur ^ 1;
    const int nk = (tt + 1) * 64;
    // tile boundary: issue first pair of next tile, then validate current tile.
    // in-flight after issue = 8 (tile tt) + 2 (newest) -> vmcnt(2) waits tile tt.
    if (tt + 1 < NT) {
      ISSUE_PAIR(nbuf, nk, 0);
      asm volatile("s_waitcnt vmcnt(2)" ::: "memory");
    } else {
      asm volatile("s_waitcnt vmcnt(0)" ::: "memory");
    }
    asm volatile("s_barrier" ::: "memory");

    short8 bf[4];
    if (tt + 1 < NT) ISSUE_PAIR(nbuf, nk, 1);
    MFMA_PHASE(cur, 0, 0, true);   // ks0, rows 0-3
    if (tt + 1 < NT) ISSUE_PAIR(nbuf, nk, 2);
    MFMA_PHASE(cur, 0, 4, false);  // ks0, rows 4-7 (bf reused)
    if (tt + 1 < NT) ISSUE_PAIR(nbuf, nk, 3);
    MFMA_PHASE(cur, 1, 0, true);   // ks1, rows 0-3
    MFMA_PHASE(cur, 1, 4, false);  // ks1, rows 4-7
  }
#undef MFMA_PHASE
#undef ISSUE_PAIR

  // epilogue: C/D map col=lane&15, row=(lane>>4)*4+r
  const int er0 = brow0 + wm * 128 + kg2 * 4;
  const int ec0 = bcol0 + wn * 64 + fr;
  if constexpr (EPI == 0) {
    unsigned short* hout = (unsigned short*)outp;
#pragma unroll
    for (int j = 0; j < 4; ++j) {
      const float bv = bias[ec0 + j * 16];
#pragma unroll
      for (int i = 0; i < 8; ++i)
#pragma unroll
        for (int r = 0; r < 4; ++r) {
          float v = acc[i][j][r] + bv;
          v = 0.5f * v * (1.0f + erff(v * 0.70710678118654752f));
          hout[(size_t)(er0 + i * 16 + r) * N1 + (ec0 + j * 16)] = f2bf(v);
        }
    }
  } else {
    float* fout = (float*)outp;
#pragma unroll
    for (int j = 0; j < 4; ++j) {
      const float bv = bias[ec0 + j * 16];
#pragma unroll
      for (int i = 0; i < 8; ++i)
#pragma unroll
        for (int r = 0; r < 4; ++r)
          fout[(size_t)(er0 + i * 16 + r) * N1 + (ec0 + j * 16)] = acc[i][j][r] + bv;
    }
  }
}

extern "C" void kernel_launch(void* const* d_in, const int* in_sizes, int n_in,
                              void* d_out, int out_size, void* d_ws, size_t ws_size,
                              hipStream_t stream) {
  const int* idxs = (const int*)d_in[0];
  const float* tok = (const float*)d_in[1];
  const float* W1 = (const float*)d_in[2];
  const float* b1 = (const float*)d_in[3];
  const float* W2 = (const float*)d_in[4];
  const float* b2 = (const float*)d_in[5];
  float* out = (float*)d_out;

  unsigned short* W1b = (unsigned short*)d_ws;                          // 4 MB
  unsigned short* W2b = (unsigned short*)((char*)d_ws + (4u << 20));    // 2 MB
  unsigned short* xb = (unsigned short*)((char*)d_ws + (6u << 20));     // 64 MB
  unsigned short* hbuf = (unsigned short*)((char*)d_ws + (70u << 20));  // 32 MB

  cvt_bf16_kernel<<<2048, 256, 0, stream>>>(W1, W1b, 524288);
  cvt_bf16_kernel<<<1024, 256, 0, stream>>>(W2, W2b, 262144);
  gather_cvt_kernel<<<16384, 256, 0, stream>>>(idxs, tok, xb);
  gemm256_kernel<2048, 0><<<256, 512, 0, stream>>>(xb, W1b, b1, hbuf);
  gemm256_kernel<1024, 1><<<256, 512, 0, stream>>>(hbuf, W2b, b2, out);
}

// Round 8
// 168.207 us; speedup vs baseline: 1.1560x; 1.1560x over previous
//
#include <hip/hip_runtime.h>
#include <hip/hip_bf16.h>

typedef __attribute__((ext_vector_type(4))) float floatx4;
typedef __attribute__((ext_vector_type(8))) short short8;
typedef __attribute__((ext_vector_type(8))) unsigned short ushortx8;

#define K1 2048
#define N1 1024

__device__ __forceinline__ unsigned short f2bf(float f) {
  __hip_bfloat16 h = __float2bfloat16(f);
  return __builtin_bit_cast(unsigned short, h);
}

__device__ __forceinline__ void gload_lds16(const void* g, void* l) {
  __builtin_amdgcn_global_load_lds(
      (__attribute__((address_space(1))) void*)const_cast<void*>(g),
      (__attribute__((address_space(3))) void*)l, 16, 0, 0);
}

__global__ void cvt_bf16_kernel(const float* __restrict__ src,
                                unsigned short* __restrict__ dst, int n4) {
  int i = blockIdx.x * blockDim.x + threadIdx.x;
  if (i >= n4) return;
  float4 f = reinterpret_cast<const float4*>(src)[i];
  ushort4 o;
  o.x = f2bf(f.x); o.y = f2bf(f.y); o.z = f2bf(f.z); o.w = f2bf(f.w);
  reinterpret_cast<ushort4*>(dst)[i] = o;
}

// Gather + fp32->bf16: xb[row][k] = bf16(tok[idxs[row]][k]). One block per row.
__global__ __launch_bounds__(256) void gather_cvt_kernel(
    const int* __restrict__ idxs, const float* __restrict__ tok,
    unsigned short* __restrict__ xb) {
  const int row = blockIdx.x;
  const float* src = tok + (size_t)idxs[row] * K1;
  unsigned short* dst = xb + (size_t)row * K1;
  const int o = threadIdx.x * 8;
  const float4 f0 = *reinterpret_cast<const float4*>(src + o);
  const float4 f1 = *reinterpret_cast<const float4*>(src + o + 4);
  ushortx8 u;
  u[0] = f2bf(f0.x); u[1] = f2bf(f0.y); u[2] = f2bf(f0.z); u[3] = f2bf(f0.w);
  u[4] = f2bf(f1.x); u[5] = f2bf(f1.y); u[6] = f2bf(f1.z); u[7] = f2bf(f1.w);
  *reinterpret_cast<ushortx8*>(dst + o) = u;
}

// 256x256-tile GEMM, BK=64, 8 waves (2Mx4N).
// Software-pipelined 4-phase K-loop: phase P's fragments are ds_read during
// phase P-1; raw s_barrier pacing (no mid-loop counter drains); all 8 stage
// loads issued right after the boundary and never waited until next boundary.
// T1 XCD swizzle, T2 swizzled LDS (via pre-swizzled global source), T5 setprio.
template <int KDIM, int EPI>
__global__ __launch_bounds__(512, 2) void gemm256_kernel(
    const unsigned short* __restrict__ A, const unsigned short* __restrict__ Bw,
    const float* __restrict__ bias, void* __restrict__ outp) {
  __shared__ unsigned short Asub[2][16384];
  __shared__ unsigned short Bsub[2][16384];
  const int t = threadIdx.x;
  const int p = blockIdx.x;
  const int bid = (p & 7) * 32 + (p >> 3);  // XCD x owns contiguous bm range
  const int bm = bid >> 2, bn = bid & 3;
  const int brow0 = bm * 256, bcol0 = bn * 256;
  const int lane = t & 63, w = t >> 6;
  const int wm = w >> 2, wn = w & 3;  // per-wave C: 128x64
  const int fr = lane & 15, kg2 = lane >> 4;

  // staging source: row r = (t>>3)+64q, global chunk cg = (t&7) ^ (r&7)
  const int srow = t >> 3;
  const int cg = (t & 7) ^ (srow & 7);
  const unsigned short* aq[4];
  const unsigned short* bq[4];
#pragma unroll
  for (int q = 0; q < 4; ++q) {
    aq[q] = A + (size_t)(brow0 + srow + 64 * q) * KDIM + cg * 8;
    bq[q] = Bw + (size_t)(bcol0 + srow + 64 * q) * KDIM + cg * 8;
  }
  const int t8 = t * 8;  // linear LDS dest (shorts)

  floatx4 acc[8][4] = {};
  constexpr int NT = KDIM / 64;

#define ISSUE_PAIR(d, k0, P)                                   \
  do {                                                         \
    gload_lds16(aq[P] + (k0), &Asub[d][t8 + (P)*4096]);        \
    gload_lds16(bq[P] + (k0), &Bsub[d][t8 + (P)*4096]);        \
  } while (0)

// fragment reads: row r at short-offset r*64; chunk c stored at slot c^(r&7)
#define READ_BF(dst, buf, KS)                                                 \
  _Pragma("unroll") for (int j = 0; j < 4; ++j)                               \
      dst[j] = *(const short8*)&Bsub[buf][(wn * 64 + j * 16 + fr) * 64 +      \
                                          (((KS)*4 + kg2) ^ (fr & 7)) * 8];

#define READ_AF(dst, buf, KS, IH)                                             \
  _Pragma("unroll") for (int i = 0; i < 4; ++i)                               \
      dst[i] = *(const short8*)&Asub[buf][(wm * 128 + ((IH)*4 + i) * 16 + fr) * 64 + \
                                          (((KS)*4 + kg2) ^ (fr & 7)) * 8];

#define MFMA16(afv, bfv, I0)                                                  \
  do {                                                                        \
    __builtin_amdgcn_s_setprio(1);                                            \
    _Pragma("unroll") for (int i = 0; i < 4; ++i)                             \
      _Pragma("unroll") for (int j = 0; j < 4; ++j)                           \
        acc[(I0) + i][j] = __builtin_amdgcn_mfma_f32_16x16x32_bf16(           \
            afv[i], bfv[j], acc[(I0) + i][j], 0, 0, 0);                       \
    __builtin_amdgcn_s_setprio(0);                                            \
  } while (0)

  // prologue: stage tile 0
  ISSUE_PAIR(0, 0, 0);
  ISSUE_PAIR(0, 0, 1);
  ISSUE_PAIR(0, 0, 2);
  ISSUE_PAIR(0, 0, 3);

#pragma unroll 1
  for (int tt = 0; tt < NT; ++tt) {
    const int cur = tt & 1;
    const int nbuf = cur ^ 1;
    // boundary: all of tile tt's loads landed; all reads of nbuf retired
    // (lgkmcnt(0)) so next-tile staging below may overwrite it.
    asm volatile("s_waitcnt vmcnt(0) lgkmcnt(0)\ns_barrier" ::: "memory");

    short8 bfA[4], bfB[4], afA[4], afB[4];
    READ_BF(bfA, cur, 0);      // phase-0 frags
    READ_AF(afA, cur, 0, 0);
    if (tt + 1 < NT) {         // stage tile tt+1; in flight until next boundary
      const int nk = (tt + 1) * 64;
      ISSUE_PAIR(nbuf, nk, 0);
      ISSUE_PAIR(nbuf, nk, 1);
      ISSUE_PAIR(nbuf, nk, 2);
      ISSUE_PAIR(nbuf, nk, 3);
    }
    READ_AF(afB, cur, 0, 1);   // phase-1 frags (under phase-0 MFMA)
    MFMA16(afA, bfA, 0);       // ks0, rows 0-3
    __builtin_amdgcn_s_barrier();
    READ_BF(bfB, cur, 1);      // phase-2 frags
    READ_AF(afA, cur, 1, 0);
    MFMA16(afB, bfA, 4);       // ks0, rows 4-7
    __builtin_amdgcn_s_barrier();
    READ_AF(afB, cur, 1, 1);   // phase-3 frags
    MFMA16(afA, bfB, 0);       // ks1, rows 0-3
    __builtin_amdgcn_s_barrier();
    MFMA16(afB, bfB, 4);       // ks1, rows 4-7
  }
#undef MFMA16
#undef READ_AF
#undef READ_BF
#undef ISSUE_PAIR

  // epilogue: C/D map col=lane&15, row=(lane>>4)*4+r
  const int er0 = brow0 + wm * 128 + kg2 * 4;
  const int ec0 = bcol0 + wn * 64 + fr;
  if constexpr (EPI == 0) {
    unsigned short* hout = (unsigned short*)outp;
#pragma unroll
    for (int j = 0; j < 4; ++j) {
      const float bv = bias[ec0 + j * 16];
#pragma unroll
      for (int i = 0; i < 8; ++i)
#pragma unroll
        for (int r = 0; r < 4; ++r) {
          float v = acc[i][j][r] + bv;
          v = 0.5f * v * (1.0f + erff(v * 0.70710678118654752f));
          hout[(size_t)(er0 + i * 16 + r) * N1 + (ec0 + j * 16)] = f2bf(v);
        }
    }
  } else {
    float* fout = (float*)outp;
#pragma unroll
    for (int j = 0; j < 4; ++j) {
      const float bv = bias[ec0 + j * 16];
#pragma unroll
      for (int i = 0; i < 8; ++i)
#pragma unroll
        for (int r = 0; r < 4; ++r)
          fout[(size_t)(er0 + i * 16 + r) * N1 + (ec0 + j * 16)] = acc[i][j][r] + bv;
    }
  }
}

extern "C" void kernel_launch(void* const* d_in, const int* in_sizes, int n_in,
                              void* d_out, int out_size, void* d_ws, size_t ws_size,
                              hipStream_t stream) {
  const int* idxs = (const int*)d_in[0];
  const float* tok = (const float*)d_in[1];
  const float* W1 = (const float*)d_in[2];
  const float* b1 = (const float*)d_in[3];
  const float* W2 = (const float*)d_in[4];
  const float* b2 = (const float*)d_in[5];
  float* out = (float*)d_out;

  unsigned short* W1b = (unsigned short*)d_ws;                          // 4 MB
  unsigned short* W2b = (unsigned short*)((char*)d_ws + (4u << 20));    // 2 MB
  unsigned short* xb = (unsigned short*)((char*)d_ws + (6u << 20));     // 64 MB
  unsigned short* hbuf = (unsigned short*)((char*)d_ws + (70u << 20));  // 32 MB

  cvt_bf16_kernel<<<2048, 256, 0, stream>>>(W1, W1b, 524288);
  cvt_bf16_kernel<<<1024, 256, 0, stream>>>(W2, W2b, 262144);
  gather_cvt_kernel<<<16384, 256, 0, stream>>>(idxs, tok, xb);
  gemm256_kernel<2048, 0><<<256, 512, 0, stream>>>(xb, W1b, b1, hbuf);
  gemm256_kernel<1024, 1><<<256, 512, 0, stream>>>(hbuf, W2b, b2, out);
}

// Round 9
// 155.543 us; speedup vs baseline: 1.2501x; 1.0814x over previous
//
#include <hip/hip_runtime.h>
#include <hip/hip_bf16.h>

typedef __attribute__((ext_vector_type(4))) float floatx4;
typedef __attribute__((ext_vector_type(8))) short short8;
typedef __attribute__((ext_vector_type(8))) unsigned short ushortx8;

#define K1 2048
#define N1 1024
#define K2 1024
#define N2 1024

__device__ __forceinline__ unsigned short f2bf(float f) {
  __hip_bfloat16 h = __float2bfloat16(f);
  return __builtin_bit_cast(unsigned short, h);
}

__device__ __forceinline__ void gload_lds16(const void* g, void* l) {
  __builtin_amdgcn_global_load_lds(
      (__attribute__((address_space(1))) void*)const_cast<void*>(g),
      (__attribute__((address_space(3))) void*)l, 16, 0, 0);
}

__global__ void cvt_bf16_kernel(const float* __restrict__ src,
                                unsigned short* __restrict__ dst, int n4) {
  int i = blockIdx.x * blockDim.x + threadIdx.x;
  if (i >= n4) return;
  float4 f = reinterpret_cast<const float4*>(src)[i];
  ushort4 o;
  o.x = f2bf(f.x); o.y = f2bf(f.y); o.z = f2bf(f.z); o.w = f2bf(f.w);
  reinterpret_cast<ushort4*>(dst)[i] = o;
}

// GEMM1 with FUSED embedding gather: h = gelu(bf16(tok[idx]) @ W1^T + b1).
// 256x256 tile, BK=64, 8 waves. A: fp32 global -> reg -> cvt -> ds_write
// (issued after boundary, written between ks0/ks1 MFMA clusters). B: gload_lds.
// LDS linear dest + XOR-pre-swizzled source chunks (rule #21). T1 XCD swizzle.
__global__ __launch_bounds__(512, 2) void gemm1_fused_kernel(
    const int* __restrict__ idxs, const float* __restrict__ tok,
    const unsigned short* __restrict__ W1b, const float* __restrict__ b1,
    unsigned short* __restrict__ hout) {
  __shared__ unsigned short Asub[2][16384];
  __shared__ unsigned short Bsub[2][16384];
  const int t = threadIdx.x;
  const int p = blockIdx.x;
  const int bid = (p & 7) * 32 + (p >> 3);  // XCD x owns contiguous bm range
  const int bm = bid >> 2, bn = bid & 3;
  const int brow0 = bm * 256, bcol0 = bn * 256;
  const int lane = t & 63, w = t >> 6;
  const int wm = w >> 2, wn = w & 3;  // per-wave C: 128x64
  const int fr = lane & 15, kg2 = lane >> 4;

  // staging: row r = (t>>3)+64q, chunk cg = (t&7)^(r&7) (8 elems of 16B-out)
  const int srow = t >> 3;
  const int cg = (t & 7) ^ (srow & 7);
  const float* aqf[4];
  const unsigned short* bq[4];
#pragma unroll
  for (int q = 0; q < 4; ++q) {
    const int ridx = idxs[brow0 + srow + 64 * q];
    aqf[q] = tok + (size_t)ridx * K1 + cg * 8;
    bq[q] = W1b + (size_t)(bcol0 + srow + 64 * q) * K1 + cg * 8;
  }
  const int t8 = t * 8;  // linear LDS dest (shorts)

  floatx4 acc[8][4] = {};
  constexpr int NT = K1 / 64;

  float4 av[4][2];
  auto loadA = [&](int k0) {
#pragma unroll
    for (int q = 0; q < 4; ++q) {
      av[q][0] = *reinterpret_cast<const float4*>(aqf[q] + k0);
      av[q][1] = *reinterpret_cast<const float4*>(aqf[q] + k0 + 4);
    }
  };
  auto writeA = [&](int d) {
#pragma unroll
    for (int q = 0; q < 4; ++q) {
      ushortx8 u;
      u[0] = f2bf(av[q][0].x); u[1] = f2bf(av[q][0].y);
      u[2] = f2bf(av[q][0].z); u[3] = f2bf(av[q][0].w);
      u[4] = f2bf(av[q][1].x); u[5] = f2bf(av[q][1].y);
      u[6] = f2bf(av[q][1].z); u[7] = f2bf(av[q][1].w);
      *reinterpret_cast<ushortx8*>(&Asub[d][t8 + q * 4096]) = u;
    }
  };
  auto issueB = [&](int d, int k0) {
#pragma unroll
    for (int q = 0; q < 4; ++q)
      gload_lds16(bq[q] + k0, &Bsub[d][t8 + q * 4096]);
  };
  auto computeKS = [&](int cur, int ks) {
    const int sl = ((ks * 4 + kg2) ^ (fr & 7)) * 8;
    short8 bf[4];
#pragma unroll
    for (int j = 0; j < 4; ++j)
      bf[j] = *(const short8*)&Bsub[cur][(wn * 64 + j * 16 + fr) * 64 + sl];
    __builtin_amdgcn_s_setprio(1);
#pragma unroll
    for (int i = 0; i < 8; ++i) {
      const short8 af = *(const short8*)&Asub[cur][(wm * 128 + i * 16 + fr) * 64 + sl];
#pragma unroll
      for (int j = 0; j < 4; ++j)
        acc[i][j] = __builtin_amdgcn_mfma_f32_16x16x32_bf16(af, bf[j], acc[i][j], 0, 0, 0);
    }
    __builtin_amdgcn_s_setprio(0);
  };

  // prologue: stage tile 0
  loadA(0);
  issueB(0, 0);
  writeA(0);  // compiler auto-waits av
  asm volatile("s_waitcnt vmcnt(0) lgkmcnt(0)\ns_barrier" ::: "memory");

#pragma unroll 1
  for (int tt = 0; tt < NT; ++tt) {
    const int cur = tt & 1;
    const int nbuf = cur ^ 1;
    const bool pf = (tt + 1 < NT);
    const int nk = (tt + 1) * 64;
    if (pf) {
      loadA(nk);        // 8 dwordx4 in flight across ks0's MFMA
      issueB(nbuf, nk); // 4 gload_lds in flight until boundary
    }
    computeKS(cur, 0);
    if (pf) writeA(nbuf);  // cvt + ds_write under ks1's window
    computeKS(cur, 1);
    // boundary: B landed (vmcnt), my ds_writes + frag reads retired (lgkm)
    asm volatile("s_waitcnt vmcnt(0) lgkmcnt(0)\ns_barrier" ::: "memory");
  }

  // epilogue: bias + exact GELU -> bf16. C/D map col=lane&15, row=(lane>>4)*4+r
  const int er0 = brow0 + wm * 128 + kg2 * 4;
  const int ec0 = bcol0 + wn * 64 + fr;
#pragma unroll
  for (int j = 0; j < 4; ++j) {
    const float bv = b1[ec0 + j * 16];
#pragma unroll
    for (int i = 0; i < 8; ++i)
#pragma unroll
      for (int r = 0; r < 4; ++r) {
        float v = acc[i][j][r] + bv;
        v = 0.5f * v * (1.0f + erff(v * 0.70710678118654752f));
        hout[(size_t)(er0 + i * 16 + r) * N1 + (ec0 + j * 16)] = f2bf(v);
      }
  }
}

// GEMM2: out = h @ W2^T + b2 (fp32 out). Round-5-proven structure.
__global__ __launch_bounds__(512, 2) void gemm2_kernel(
    const unsigned short* __restrict__ A, const unsigned short* __restrict__ Bw,
    const float* __restrict__ bias, float* __restrict__ out) {
  __shared__ unsigned short Asub[2][16384];
  __shared__ unsigned short Bsub[2][16384];
  const int t = threadIdx.x;
  const int p = blockIdx.x;
  const int bid = (p & 7) * 32 + (p >> 3);
  const int bm = bid >> 2, bn = bid & 3;
  const int brow0 = bm * 256, bcol0 = bn * 256;
  const int lane = t & 63, w = t >> 6;
  const int wm = w >> 2, wn = w & 3;
  const int fr = lane & 15, kg2 = lane >> 4;

  const int srow = t >> 3;
  const int cg = (t & 7) ^ (srow & 7);
  const unsigned short* aq[4];
  const unsigned short* bq[4];
#pragma unroll
  for (int q = 0; q < 4; ++q) {
    aq[q] = A + (size_t)(brow0 + srow + 64 * q) * K2 + cg * 8;
    bq[q] = Bw + (size_t)(bcol0 + srow + 64 * q) * K2 + cg * 8;
  }
  const int t8 = t * 8;

  const int arow_sh = (wm * 128 + fr) * 64;
  const int brow_sh = (wn * 64 + fr) * 64;

  floatx4 acc[8][4] = {};
  constexpr int NT = K2 / 64;

  auto stage = [&](int d, int k0) {
#pragma unroll
    for (int q = 0; q < 4; ++q) {
      gload_lds16(aq[q] + k0, &Asub[d][t8 + q * 4096]);
      gload_lds16(bq[q] + k0, &Bsub[d][t8 + q * 4096]);
    }
  };
  auto compute = [&](int cur) {
#pragma unroll
    for (int ks = 0; ks < 2; ++ks) {
      const int sl = ((ks * 4 + kg2) ^ (fr & 7)) * 8;
      short8 bf[4];
#pragma unroll
      for (int j = 0; j < 4; ++j)
        bf[j] = *reinterpret_cast<const short8*>(&Bsub[cur][brow_sh + j * 1024 + sl]);
#pragma unroll
      for (int i = 0; i < 8; ++i) {
        const short8 af = *reinterpret_cast<const short8*>(&Asub[cur][arow_sh + i * 1024 + sl]);
#pragma unroll
        for (int j = 0; j < 4; ++j)
          acc[i][j] = __builtin_amdgcn_mfma_f32_16x16x32_bf16(af, bf[j], acc[i][j], 0, 0, 0);
      }
    }
  };

  stage(0, 0);
#pragma unroll 1
  for (int it = 0; it < NT - 1; ++it) {
    const int cur = it & 1;
    stage(cur ^ 1, (it + 1) * 64);
    asm volatile("s_waitcnt vmcnt(8)\ns_barrier" ::: "memory");
    compute(cur);
    asm volatile("s_waitcnt lgkmcnt(0)\ns_barrier" ::: "memory");
  }
  asm volatile("s_waitcnt vmcnt(0)\ns_barrier" ::: "memory");
  compute((NT - 1) & 1);

  const int er0 = brow0 + wm * 128 + kg2 * 4;
  const int ec0 = bcol0 + wn * 64 + fr;
#pragma unroll
  for (int j = 0; j < 4; ++j) {
    const float bv = bias[ec0 + j * 16];
#pragma unroll
    for (int i = 0; i < 8; ++i)
#pragma unroll
      for (int r = 0; r < 4; ++r)
        out[(size_t)(er0 + i * 16 + r) * N2 + (ec0 + j * 16)] = acc[i][j][r] + bv;
  }
}

extern "C" void kernel_launch(void* const* d_in, const int* in_sizes, int n_in,
                              void* d_out, int out_size, void* d_ws, size_t ws_size,
                              hipStream_t stream) {
  const int* idxs = (const int*)d_in[0];
  const float* tok = (const float*)d_in[1];
  const float* W1 = (const float*)d_in[2];
  const float* b1 = (const float*)d_in[3];
  const float* W2 = (const float*)d_in[4];
  const float* b2 = (const float*)d_in[5];
  float* out = (float*)d_out;

  unsigned short* W1b = (unsigned short*)d_ws;                          // 4 MB
  unsigned short* W2b = (unsigned short*)((char*)d_ws + (4u << 20));    // 2 MB
  unsigned short* hbuf = (unsigned short*)((char*)d_ws + (6u << 20));   // 32 MB

  cvt_bf16_kernel<<<2048, 256, 0, stream>>>(W1, W1b, 524288);
  cvt_bf16_kernel<<<1024, 256, 0, stream>>>(W2, W2b, 262144);
  gemm1_fused_kernel<<<256, 512, 0, stream>>>(idxs, tok, W1b, b1, hbuf);
  gemm2_kernel<<<256, 512, 0, stream>>>(hbuf, W2b, b2, out);
}